// Round 1
// baseline (1538.406 us; speedup 1.0000x reference)
//
#include <hip/hip_runtime.h>

#define NNODES 100000
#define NEDGES 1600000
// DIN = DH = 128, DC = 64

// ---------------- CSR build ----------------

__global__ __launch_bounds__(256) void k_deg(const int* __restrict__ dst, int* __restrict__ deg) {
    int e = blockIdx.x * 256 + threadIdx.x;
    if (e < NEDGES) atomicAdd(&deg[dst[e]], 1);
}

// single-block scan: thread t owns a contiguous chunk; sequential local scan +
// one 1024-wide block scan of chunk sums.
__global__ __launch_bounds__(1024) void k_scan(const int* __restrict__ deg, int* __restrict__ row_ptr,
                                               int* __restrict__ cursor, float* __restrict__ deg_inv) {
    constexpr int C = (NNODES + 1023) / 1024;  // 98
    __shared__ int lds[1024];
    int t = threadIdx.x;
    int beg = t * C;
    int end = beg + C; if (end > NNODES) end = NNODES;
    int sum = 0;
    for (int i = beg; i < end; ++i) sum += deg[i];
    lds[t] = sum;
    __syncthreads();
    for (int off = 1; off < 1024; off <<= 1) {
        int v = (t >= off) ? lds[t - off] : 0;
        __syncthreads();
        lds[t] += v;
        __syncthreads();
    }
    int excl = lds[t] - sum;   // exclusive prefix of this thread's chunk
    int run = excl;
    for (int i = beg; i < end; ++i) {
        int v = deg[i];
        row_ptr[i] = run;
        cursor[i]  = run;
        deg_inv[i] = 1.0f / fmaxf((float)v, 1.0f);
        run += v;
    }
    if (t == 0) row_ptr[NNODES] = lds[1023];
}

__global__ __launch_bounds__(256) void k_scatter(const int* __restrict__ src, const int* __restrict__ dst,
                                                 int* __restrict__ cursor, int* __restrict__ edge_src) {
    int e = blockIdx.x * 256 + threadIdx.x;
    if (e < NEDGES) {
        int pos = atomicAdd(&cursor[dst[e]], 1);
        edge_src[pos] = src[e];
    }
}

// ---------------- mean-aggregate: one wave per node ----------------
// lane holds float2 -> 64 lanes cover 128 features; each neighbor row is one
// coalesced 512B wave read.
__global__ __launch_bounds__(256) void k_aggregate(const float* __restrict__ h,
                                                   const int* __restrict__ row_ptr,
                                                   const int* __restrict__ edge_src,
                                                   const float* __restrict__ deg_inv,
                                                   float* __restrict__ agg) {
    int node = blockIdx.x * 4 + (threadIdx.x >> 6);
    int lane = threadIdx.x & 63;
    int beg = row_ptr[node];
    int end = row_ptr[node + 1];
    const float2* hb = (const float2*)h;
    float2 acc = make_float2(0.f, 0.f);
    for (int p = beg; p < end; ++p) {
        int s = edge_src[p];                    // wave-uniform -> scalar load
        float2 v = hb[(size_t)s * 64 + lane];
        acc.x += v.x;
        acc.y += v.y;
    }
    float di = deg_inv[node];
    ((float2*)agg)[(size_t)node * 64 + lane] = make_float2(acc.x * di, acc.y * di);
}

// ---------------- fused dual-GEMM + bias (+relu) ----------------
// out[i,:] = Ah[i,:]@Ws + Aa[i,:]@Wn + b   (K = 128+128, COLS = 128 or 64)
// 32 rows per block, 256 threads, thread = 4 rows x TN cols.
template <int COLS, bool RELU>
__global__ __launch_bounds__(256) void k_gemm(const float* __restrict__ Ah, const float* __restrict__ Aa,
                                              const float* __restrict__ Ws, const float* __restrict__ Wn,
                                              const float* __restrict__ bias, float* __restrict__ out) {
    constexpr int TN = COLS / 32;            // 4 (COLS=128) or 2 (COLS=64)
    __shared__ float A[256 * 33];            // [k][r], r padded 32->33: write banks (k+r)%32
    const int tx = threadIdx.x;
    const int row0 = blockIdx.x * 32;

    // stage: lane tx owns feature k=tx (h for k<128, agg for k>=128), loops rows
    {
        const float* srcp = (tx < 128) ? (Ah + tx) : (Aa + (tx - 128));
#pragma unroll 4
        for (int r = 0; r < 32; ++r) {
            A[tx * 33 + r] = srcp[(size_t)(row0 + r) * 128];
        }
    }
    __syncthreads();

    const int colt = tx & 31;
    const int rowt = tx >> 5;
    const int c0 = colt * TN;
    const int r0 = rowt * 4;

    float acc[4][TN];
#pragma unroll
    for (int r = 0; r < 4; ++r)
#pragma unroll
        for (int j = 0; j < TN; ++j) acc[r][j] = 0.f;

    const float* Whalf[2] = {Ws, Wn};
#pragma unroll
    for (int half = 0; half < 2; ++half) {
        const float* __restrict__ W = Whalf[half];
#pragma unroll 2
        for (int kk = 0; kk < 128; ++kk) {
            const int k = half * 128 + kk;
            float w[TN];
#pragma unroll
            for (int j = 0; j < TN; ++j) w[j] = W[kk * COLS + c0 + j];
            const float* Ak = &A[k * 33 + r0];
#pragma unroll
            for (int r = 0; r < 4; ++r) {
                const float a = Ak[r];
#pragma unroll
                for (int j = 0; j < TN; ++j) acc[r][j] += a * w[j];
            }
        }
    }

#pragma unroll
    for (int r = 0; r < 4; ++r) {
#pragma unroll
        for (int j = 0; j < TN; ++j) {
            float v = acc[r][j] + bias[c0 + j];
            if (RELU) v = fmaxf(v, 0.f);
            out[(size_t)(row0 + r0 + r) * COLS + c0 + j] = v;
        }
    }
}

// ---------------- launch ----------------

extern "C" void kernel_launch(void* const* d_in, const int* in_sizes, int n_in,
                              void* d_out, int out_size, void* d_ws, size_t ws_size,
                              hipStream_t stream) {
    const float* x   = (const float*)d_in[0];
    const int*   src = (const int*)d_in[1];
    const int*   dst = (const int*)d_in[2];
    const float* Ws0 = (const float*)d_in[3];
    const float* Wn0 = (const float*)d_in[4];
    const float* b0  = (const float*)d_in[5];
    const float* Ws1 = (const float*)d_in[6];
    const float* Wn1 = (const float*)d_in[7];
    const float* b1  = (const float*)d_in[8];
    const float* Ws2 = (const float*)d_in[9];
    const float* Wn2 = (const float*)d_in[10];
    const float* b2  = (const float*)d_in[11];
    float* out = (float*)d_out;

    char* ws = (char*)d_ws;
    size_t off = 0;
    auto alloc = [&](size_t bytes) -> void* {
        off = (off + 255) & ~(size_t)255;
        void* p = ws + off;
        off += bytes;
        return p;
    };
    int*   deg      = (int*)alloc((size_t)NNODES * 4);
    int*   row_ptr  = (int*)alloc((size_t)(NNODES + 1) * 4);
    int*   cursor   = (int*)alloc((size_t)NNODES * 4);
    float* deg_inv  = (float*)alloc((size_t)NNODES * 4);
    int*   edge_src = (int*)alloc((size_t)NEDGES * 4);
    float* agg      = (float*)alloc((size_t)NNODES * 128 * 4);
    float* h1       = (float*)alloc((size_t)NNODES * 128 * 4);
    float* h2       = (float*)alloc((size_t)NNODES * 128 * 4);
    (void)ws_size; (void)n_in; (void)in_sizes; (void)out_size;

    // CSR build (per call — ws is re-poisoned every launch)
    hipMemsetAsync(deg, 0, (size_t)NNODES * 4, stream);
    k_deg<<<(NEDGES + 255) / 256, 256, 0, stream>>>(dst, deg);
    k_scan<<<1, 1024, 0, stream>>>(deg, row_ptr, cursor, deg_inv);
    k_scatter<<<(NEDGES + 255) / 256, 256, 0, stream>>>(src, dst, cursor, edge_src);

    // layer 0: x -> h1
    k_aggregate<<<NNODES / 4, 256, 0, stream>>>(x, row_ptr, edge_src, deg_inv, agg);
    k_gemm<128, true><<<NNODES / 32, 256, 0, stream>>>(x, agg, Ws0, Wn0, b0, h1);
    // layer 1: h1 -> h2
    k_aggregate<<<NNODES / 4, 256, 0, stream>>>(h1, row_ptr, edge_src, deg_inv, agg);
    k_gemm<128, true><<<NNODES / 32, 256, 0, stream>>>(h1, agg, Ws1, Wn1, b1, h2);
    // layer 2: h2 -> out
    k_aggregate<<<NNODES / 4, 256, 0, stream>>>(h2, row_ptr, edge_src, deg_inv, agg);
    k_gemm<64, false><<<NNODES / 32, 256, 0, stream>>>(h2, agg, Ws2, Wn2, b2, out);
}

// Round 2
// 1276.362 us; speedup vs baseline: 1.2053x; 1.2053x over previous
//
#include <hip/hip_runtime.h>

#define NNODES 100000
#define NEDGES 1600000
#define NBLK_SCAN ((NNODES + 255) / 256)   // 391
// DIN = DH = 128, DC = 64

// ---------------- CSR build ----------------

__global__ __launch_bounds__(256) void k_deg(const int* __restrict__ dst, int* __restrict__ deg) {
    int e = blockIdx.x * 256 + threadIdx.x;
    if (e < NEDGES) atomicAdd(&deg[dst[e]], 1);
}

// scan stage 1: per-block sums of deg
__global__ __launch_bounds__(256) void k_partial(const int* __restrict__ deg, int* __restrict__ partial) {
    int i = blockIdx.x * 256 + threadIdx.x;
    int v = (i < NNODES) ? deg[i] : 0;
#pragma unroll
    for (int off = 32; off > 0; off >>= 1) v += __shfl_down(v, off, 64);
    __shared__ int s[4];
    if ((threadIdx.x & 63) == 0) s[threadIdx.x >> 6] = v;
    __syncthreads();
    if (threadIdx.x == 0) partial[blockIdx.x] = s[0] + s[1] + s[2] + s[3];
}

// scan stage 2: exclusive-scan the 391 partials in one block
__global__ __launch_bounds__(512) void k_scanpart(int* __restrict__ partial) {
    __shared__ int lds[512];
    int t = threadIdx.x;
    int v = (t < NBLK_SCAN) ? partial[t] : 0;
    lds[t] = v;
    __syncthreads();
#pragma unroll
    for (int off = 1; off < 512; off <<= 1) {
        int u = (t >= off) ? lds[t - off] : 0;
        __syncthreads();
        lds[t] += u;
        __syncthreads();
    }
    if (t < NBLK_SCAN) partial[t] = lds[t] - v;   // exclusive prefix
}

// scan stage 3: per-block LDS scan + partial offset -> row_ptr/cursor/deg_inv
__global__ __launch_bounds__(256) void k_apply(const int* __restrict__ deg, const int* __restrict__ partial,
                                               int* __restrict__ row_ptr, int* __restrict__ cursor,
                                               float* __restrict__ deg_inv) {
    __shared__ int lds[256];
    int t = threadIdx.x;
    int i = blockIdx.x * 256 + t;
    int v = (i < NNODES) ? deg[i] : 0;
    lds[t] = v;
    __syncthreads();
#pragma unroll
    for (int off = 1; off < 256; off <<= 1) {
        int u = (t >= off) ? lds[t - off] : 0;
        __syncthreads();
        lds[t] += u;
        __syncthreads();
    }
    if (i < NNODES) {
        int excl = lds[t] - v + partial[blockIdx.x];
        row_ptr[i] = excl;
        cursor[i]  = excl;
        deg_inv[i] = 1.0f / fmaxf((float)v, 1.0f);
    }
    if (i == NNODES - 1) row_ptr[NNODES] = NEDGES;
}

__global__ __launch_bounds__(256) void k_scatter(const int* __restrict__ src, const int* __restrict__ dst,
                                                 int* __restrict__ cursor, int* __restrict__ edge_src) {
    int e = blockIdx.x * 256 + threadIdx.x;
    if (e < NEDGES) {
        int pos = atomicAdd(&cursor[dst[e]], 1);
        edge_src[pos] = src[e];
    }
}

// ---------------- mean-aggregate: one wave per node ----------------
__global__ __launch_bounds__(256) void k_aggregate(const float* __restrict__ h,
                                                   const int* __restrict__ row_ptr,
                                                   const int* __restrict__ edge_src,
                                                   const float* __restrict__ deg_inv,
                                                   float* __restrict__ agg) {
    int node = blockIdx.x * 4 + (threadIdx.x >> 6);
    int lane = threadIdx.x & 63;
    int beg = row_ptr[node];
    int end = row_ptr[node + 1];
    const float2* hb = (const float2*)h;
    float2 acc = make_float2(0.f, 0.f);
    for (int p = beg; p < end; ++p) {
        int s = edge_src[p];                    // wave-uniform -> scalar load
        float2 v = hb[(size_t)s * 64 + lane];
        acc.x += v.x;
        acc.y += v.y;
    }
    float di = deg_inv[node];
    ((float2*)agg)[(size_t)node * 64 + lane] = make_float2(acc.x * di, acc.y * di);
}

// ---------------- fused dual-GEMM + bias (+relu) ----------------
// out[i,:] = Ah[i,:]@Ws + Aa[i,:]@Wn + b   (K = 128+128, COLS = 128 or 64)
template <int COLS, bool RELU>
__global__ __launch_bounds__(256) void k_gemm(const float* __restrict__ Ah, const float* __restrict__ Aa,
                                              const float* __restrict__ Ws, const float* __restrict__ Wn,
                                              const float* __restrict__ bias, float* __restrict__ out) {
    constexpr int TN = COLS / 32;            // 4 (COLS=128) or 2 (COLS=64)
    __shared__ float A[256 * 33];            // [k][r], r padded 32->33
    const int tx = threadIdx.x;
    const int row0 = blockIdx.x * 32;

    {
        const float* srcp = (tx < 128) ? (Ah + tx) : (Aa + (tx - 128));
#pragma unroll 4
        for (int r = 0; r < 32; ++r) {
            A[tx * 33 + r] = srcp[(size_t)(row0 + r) * 128];
        }
    }
    __syncthreads();

    const int colt = tx & 31;
    const int rowt = tx >> 5;
    const int c0 = colt * TN;
    const int r0 = rowt * 4;

    float acc[4][TN];
#pragma unroll
    for (int r = 0; r < 4; ++r)
#pragma unroll
        for (int j = 0; j < TN; ++j) acc[r][j] = 0.f;

    const float* Whalf[2] = {Ws, Wn};
#pragma unroll
    for (int half = 0; half < 2; ++half) {
        const float* __restrict__ W = Whalf[half];
#pragma unroll 2
        for (int kk = 0; kk < 128; ++kk) {
            const int k = half * 128 + kk;
            float w[TN];
#pragma unroll
            for (int j = 0; j < TN; ++j) w[j] = W[kk * COLS + c0 + j];
            const float* Ak = &A[k * 33 + r0];
#pragma unroll
            for (int r = 0; r < 4; ++r) {
                const float a = Ak[r];
#pragma unroll
                for (int j = 0; j < TN; ++j) acc[r][j] += a * w[j];
            }
        }
    }

#pragma unroll
    for (int r = 0; r < 4; ++r) {
#pragma unroll
        for (int j = 0; j < TN; ++j) {
            float v = acc[r][j] + bias[c0 + j];
            if (RELU) v = fmaxf(v, 0.f);
            out[(size_t)(row0 + r0 + r) * COLS + c0 + j] = v;
        }
    }
}

// ---------------- launch ----------------

extern "C" void kernel_launch(void* const* d_in, const int* in_sizes, int n_in,
                              void* d_out, int out_size, void* d_ws, size_t ws_size,
                              hipStream_t stream) {
    const float* x   = (const float*)d_in[0];
    const int*   src = (const int*)d_in[1];
    const int*   dst = (const int*)d_in[2];
    const float* Ws0 = (const float*)d_in[3];
    const float* Wn0 = (const float*)d_in[4];
    const float* b0  = (const float*)d_in[5];
    const float* Ws1 = (const float*)d_in[6];
    const float* Wn1 = (const float*)d_in[7];
    const float* b1  = (const float*)d_in[8];
    const float* Ws2 = (const float*)d_in[9];
    const float* Wn2 = (const float*)d_in[10];
    const float* b2  = (const float*)d_in[11];
    float* out = (float*)d_out;

    char* ws = (char*)d_ws;
    size_t off = 0;
    auto alloc = [&](size_t bytes) -> void* {
        off = (off + 255) & ~(size_t)255;
        void* p = ws + off;
        off += bytes;
        return p;
    };
    int*   deg      = (int*)alloc((size_t)NNODES * 4);
    int*   row_ptr  = (int*)alloc((size_t)(NNODES + 1) * 4);
    int*   cursor   = (int*)alloc((size_t)NNODES * 4);
    float* deg_inv  = (float*)alloc((size_t)NNODES * 4);
    int*   edge_src = (int*)alloc((size_t)NEDGES * 4);
    int*   partial  = (int*)alloc((size_t)NBLK_SCAN * 4);
    float* agg      = (float*)alloc((size_t)NNODES * 128 * 4);
    float* h1       = (float*)alloc((size_t)NNODES * 128 * 4);
    float* h2       = (float*)alloc((size_t)NNODES * 128 * 4);
    (void)ws_size; (void)n_in; (void)in_sizes; (void)out_size;

    // CSR build (per call — ws is re-poisoned every launch)
    hipMemsetAsync(deg, 0, (size_t)NNODES * 4, stream);
    k_deg<<<(NEDGES + 255) / 256, 256, 0, stream>>>(dst, deg);
    k_partial<<<NBLK_SCAN, 256, 0, stream>>>(deg, partial);
    k_scanpart<<<1, 512, 0, stream>>>(partial);
    k_apply<<<NBLK_SCAN, 256, 0, stream>>>(deg, partial, row_ptr, cursor, deg_inv);
    k_scatter<<<(NEDGES + 255) / 256, 256, 0, stream>>>(src, dst, cursor, edge_src);

    // layer 0: x -> h1
    k_aggregate<<<NNODES / 4, 256, 0, stream>>>(x, row_ptr, edge_src, deg_inv, agg);
    k_gemm<128, true><<<NNODES / 32, 256, 0, stream>>>(x, agg, Ws0, Wn0, b0, h1);
    // layer 1: h1 -> h2
    k_aggregate<<<NNODES / 4, 256, 0, stream>>>(h1, row_ptr, edge_src, deg_inv, agg);
    k_gemm<128, true><<<NNODES / 32, 256, 0, stream>>>(h1, agg, Ws1, Wn1, b1, h2);
    // layer 2: h2 -> out
    k_aggregate<<<NNODES / 4, 256, 0, stream>>>(h2, row_ptr, edge_src, deg_inv, agg);
    k_gemm<64, false><<<NNODES / 32, 256, 0, stream>>>(h2, agg, Ws2, Wn2, b2, out);
}

// Round 3
// 620.650 us; speedup vs baseline: 2.4787x; 2.0565x over previous
//
#include <hip/hip_runtime.h>
#include <hip/hip_fp16.h>

#define NNODES 100000
#define NPAD   100032            // 64*1563, padded so GEMM A-loads need no mask
#define NEDGES 1600000
#define NBLK_SCAN ((NNODES + 255) / 256)   // 391
#define NBLK_GEMM (NPAD / 64)              // 1563

typedef _Float16 half8 __attribute__((ext_vector_type(8)));
typedef float floatx4 __attribute__((ext_vector_type(4)));

// ---------------- CSR build ----------------

__global__ __launch_bounds__(256) void k_deg(const int* __restrict__ dst, int* __restrict__ deg) {
    int e = blockIdx.x * 256 + threadIdx.x;
    if (e < NEDGES) atomicAdd(&deg[dst[e]], 1);
}

__global__ __launch_bounds__(256) void k_partial(const int* __restrict__ deg, int* __restrict__ partial) {
    int i = blockIdx.x * 256 + threadIdx.x;
    int v = (i < NNODES) ? deg[i] : 0;
#pragma unroll
    for (int off = 32; off > 0; off >>= 1) v += __shfl_down(v, off, 64);
    __shared__ int s[4];
    if ((threadIdx.x & 63) == 0) s[threadIdx.x >> 6] = v;
    __syncthreads();
    if (threadIdx.x == 0) partial[blockIdx.x] = s[0] + s[1] + s[2] + s[3];
}

__global__ __launch_bounds__(512) void k_scanpart(int* __restrict__ partial) {
    __shared__ int lds[512];
    int t = threadIdx.x;
    int v = (t < NBLK_SCAN) ? partial[t] : 0;
    lds[t] = v;
    __syncthreads();
#pragma unroll
    for (int off = 1; off < 512; off <<= 1) {
        int u = (t >= off) ? lds[t - off] : 0;
        __syncthreads();
        lds[t] += u;
        __syncthreads();
    }
    if (t < NBLK_SCAN) partial[t] = lds[t] - v;
}

__global__ __launch_bounds__(256) void k_apply(const int* __restrict__ deg, const int* __restrict__ partial,
                                               int* __restrict__ row_ptr, int* __restrict__ cursor,
                                               float* __restrict__ deg_inv) {
    __shared__ int lds[256];
    int t = threadIdx.x;
    int i = blockIdx.x * 256 + t;
    int v = (i < NNODES) ? deg[i] : 0;
    lds[t] = v;
    __syncthreads();
#pragma unroll
    for (int off = 1; off < 256; off <<= 1) {
        int u = (t >= off) ? lds[t - off] : 0;
        __syncthreads();
        lds[t] += u;
        __syncthreads();
    }
    if (i < NNODES) {
        int excl = lds[t] - v + partial[blockIdx.x];
        row_ptr[i] = excl;
        cursor[i]  = excl;
        deg_inv[i] = 1.0f / fmaxf((float)v, 1.0f);
    }
    if (i == NNODES - 1) row_ptr[NNODES] = NEDGES;
}

__global__ __launch_bounds__(256) void k_scatter(const int* __restrict__ src, const int* __restrict__ dst,
                                                 int* __restrict__ cursor, int* __restrict__ edge_src) {
    int e = blockIdx.x * 256 + threadIdx.x;
    if (e < NEDGES) {
        int pos = atomicAdd(&cursor[dst[e]], 1);
        edge_src[pos] = src[e];
    }
}

// ---------------- fp32 -> fp16 feature conversion ----------------
__global__ __launch_bounds__(256) void k_f2h(const float* __restrict__ x, __half* __restrict__ x16) {
    int i = blockIdx.x * 256 + threadIdx.x;       // one float4 -> 4 halfs
    if (i < NNODES * 32) {
        float4 v = ((const float4*)x)[i];
        __half2* o = (__half2*)(x16 + (size_t)i * 4);
        o[0] = __floats2half2_rn(v.x, v.y);
        o[1] = __floats2half2_rn(v.z, v.w);
    }
}

// ---------------- W pre-shuffle into MFMA B-fragment order ----------------
// Wb stored as half8[(kstep*NCT + ctile)*64 + lane]; element j is
// W[kstep*32 + (lane>>4)*8 + j][ctile*16 + (lane&15)], rows 0..127 from Ws, 128..255 from Wn.
template <int COLS>
__global__ __launch_bounds__(256) void k_wshuf(const float* __restrict__ Ws, const float* __restrict__ Wn,
                                               __half* __restrict__ Wb) {
    constexpr int NCT = COLS / 16;
    int t = blockIdx.x * 256 + threadIdx.x;
    if (t >= 8 * NCT * 64) return;
    int lane  = t & 63;
    int ctile = (t >> 6) % NCT;
    int kstep = t / (64 * NCT);
    int n  = ctile * 16 + (lane & 15);
    int k0 = kstep * 32 + (lane >> 4) * 8;
    half8 w8;
#pragma unroll
    for (int j = 0; j < 8; ++j) {
        int k = k0 + j;
        float w = (k < 128) ? Ws[k * COLS + n] : Wn[(k - 128) * COLS + n];
        w8[j] = (_Float16)w;
    }
    ((half8*)Wb)[t] = w8;
}

// ---------------- mean-aggregate (fp16 rows, fp32 accumulate) ----------------
__global__ __launch_bounds__(256) void k_aggregate16(const __half* __restrict__ h,
                                                     const int* __restrict__ row_ptr,
                                                     const int* __restrict__ edge_src,
                                                     const float* __restrict__ deg_inv,
                                                     __half* __restrict__ agg) {
    int node = blockIdx.x * 4 + (threadIdx.x >> 6);
    int lane = threadIdx.x & 63;
    int beg = row_ptr[node];
    int end = row_ptr[node + 1];
    const __half2* hb = (const __half2*)h;
    float2 a0 = {0.f, 0.f}, a1 = {0.f, 0.f}, a2 = {0.f, 0.f}, a3 = {0.f, 0.f};
    int p = beg;
    for (; p + 4 <= end; p += 4) {
        int s0 = edge_src[p], s1 = edge_src[p + 1], s2 = edge_src[p + 2], s3 = edge_src[p + 3];
        float2 v0 = __half22float2(hb[(size_t)s0 * 64 + lane]);
        float2 v1 = __half22float2(hb[(size_t)s1 * 64 + lane]);
        float2 v2 = __half22float2(hb[(size_t)s2 * 64 + lane]);
        float2 v3 = __half22float2(hb[(size_t)s3 * 64 + lane]);
        a0.x += v0.x; a0.y += v0.y;
        a1.x += v1.x; a1.y += v1.y;
        a2.x += v2.x; a2.y += v2.y;
        a3.x += v3.x; a3.y += v3.y;
    }
    for (; p < end; ++p) {
        int s = edge_src[p];
        float2 v = __half22float2(hb[(size_t)s * 64 + lane]);
        a0.x += v.x; a0.y += v.y;
    }
    float di = deg_inv[node];
    float sx = (a0.x + a1.x) + (a2.x + a3.x);
    float sy = (a0.y + a1.y) + (a2.y + a3.y);
    ((__half2*)agg)[(size_t)node * 64 + lane] = __floats2half2_rn(sx * di, sy * di);
}

// ---------------- MFMA dual-GEMM + bias (+relu) ----------------
// C[i,:] = [Ah(i,:)|Aa(i,:)] @ Wb + bias ; per-wave 16 rows x COLS, K=256 in 8 steps.
template <int COLS, bool RELU, bool OUT16>
__global__ __launch_bounds__(256) void k_gemm_mfma(const __half* __restrict__ Ah,
                                                   const __half* __restrict__ Aa,
                                                   const __half* __restrict__ Wb,
                                                   const float* __restrict__ bias,
                                                   void* __restrict__ outv) {
    constexpr int NCT = COLS / 16;
    int lane = threadIdx.x & 63;
    int wave = threadIdx.x >> 6;
    int row0 = blockIdx.x * 64 + wave * 16;
    int m = lane & 15, quad = lane >> 4;
    // A fragment base: row (row0+m), byte col offset quad*8 halfs; kstep advances 32 halfs = 4 half8
    const half8* Aq_h = (const half8*)(Ah + (size_t)(row0 + m) * 128 + quad * 8);
    const half8* Aq_a = (const half8*)(Aa + (size_t)(row0 + m) * 128 + quad * 8);
    const half8* Bq = (const half8*)Wb;

    floatx4 acc[NCT];
#pragma unroll
    for (int c = 0; c < NCT; ++c) acc[c] = floatx4{0.f, 0.f, 0.f, 0.f};

#pragma unroll
    for (int ks = 0; ks < 8; ++ks) {
        half8 a = (ks < 4) ? Aq_h[ks * 4] : Aq_a[(ks - 4) * 4];
#pragma unroll
        for (int c = 0; c < NCT; ++c) {
            half8 b = Bq[(size_t)(ks * NCT + c) * 64 + lane];
            acc[c] = __builtin_amdgcn_mfma_f32_16x16x32_f16(a, b, acc[c], 0, 0, 0);
        }
    }

#pragma unroll
    for (int c = 0; c < NCT; ++c) {
        int col = c * 16 + m;
        float bv = bias[col];
#pragma unroll
        for (int r = 0; r < 4; ++r) {
            int row = row0 + quad * 4 + r;
            float v = acc[c][r] + bv;
            if (RELU) v = fmaxf(v, 0.f);
            if (row < NNODES) {
                if (OUT16) ((__half*)outv)[(size_t)row * COLS + col] = __float2half(v);
                else       ((float*)outv)[(size_t)row * COLS + col] = v;
            }
        }
    }
}

// ---------------- launch ----------------

extern "C" void kernel_launch(void* const* d_in, const int* in_sizes, int n_in,
                              void* d_out, int out_size, void* d_ws, size_t ws_size,
                              hipStream_t stream) {
    const float* x   = (const float*)d_in[0];
    const int*   src = (const int*)d_in[1];
    const int*   dst = (const int*)d_in[2];
    const float* Ws0 = (const float*)d_in[3];
    const float* Wn0 = (const float*)d_in[4];
    const float* b0  = (const float*)d_in[5];
    const float* Ws1 = (const float*)d_in[6];
    const float* Wn1 = (const float*)d_in[7];
    const float* b1  = (const float*)d_in[8];
    const float* Ws2 = (const float*)d_in[9];
    const float* Wn2 = (const float*)d_in[10];
    const float* b2  = (const float*)d_in[11];
    float* out = (float*)d_out;

    char* ws = (char*)d_ws;
    size_t off = 0;
    auto alloc = [&](size_t bytes) -> void* {
        off = (off + 255) & ~(size_t)255;
        void* p = ws + off;
        off += bytes;
        return p;
    };
    int*    deg      = (int*)alloc((size_t)NNODES * 4);
    int*    row_ptr  = (int*)alloc((size_t)(NNODES + 1) * 4);
    int*    cursor   = (int*)alloc((size_t)NNODES * 4);
    float*  deg_inv  = (float*)alloc((size_t)NNODES * 4);
    int*    edge_src = (int*)alloc((size_t)NEDGES * 4);
    int*    partial  = (int*)alloc((size_t)NBLK_SCAN * 4);
    __half* x16      = (__half*)alloc((size_t)NPAD * 128 * 2);
    __half* agg16    = (__half*)alloc((size_t)NPAD * 128 * 2);
    __half* h1       = (__half*)alloc((size_t)NPAD * 128 * 2);
    __half* h2       = (__half*)alloc((size_t)NPAD * 128 * 2);
    __half* Wb0      = (__half*)alloc((size_t)8 * 8 * 64 * 8 * 2);
    __half* Wb1      = (__half*)alloc((size_t)8 * 8 * 64 * 8 * 2);
    __half* Wb2      = (__half*)alloc((size_t)8 * 4 * 64 * 8 * 2);
    (void)ws_size; (void)n_in; (void)in_sizes; (void)out_size;

    // CSR build
    hipMemsetAsync(deg, 0, (size_t)NNODES * 4, stream);
    k_deg<<<(NEDGES + 255) / 256, 256, 0, stream>>>(dst, deg);
    k_partial<<<NBLK_SCAN, 256, 0, stream>>>(deg, partial);
    k_scanpart<<<1, 512, 0, stream>>>(partial);
    k_apply<<<NBLK_SCAN, 256, 0, stream>>>(deg, partial, row_ptr, cursor, deg_inv);
    k_scatter<<<(NEDGES + 255) / 256, 256, 0, stream>>>(src, dst, cursor, edge_src);

    // conversions (x -> fp16, W -> pre-shuffled fp16 B-fragments)
    k_f2h<<<(NNODES * 32 + 255) / 256, 256, 0, stream>>>(x, x16);
    k_wshuf<128><<<(8 * 8 * 64 + 255) / 256, 256, 0, stream>>>(Ws0, Wn0, Wb0);
    k_wshuf<128><<<(8 * 8 * 64 + 255) / 256, 256, 0, stream>>>(Ws1, Wn1, Wb1);
    k_wshuf<64><<<(8 * 4 * 64 + 255) / 256, 256, 0, stream>>>(Ws2, Wn2, Wb2);

    // layer 0: x16 -> h1
    k_aggregate16<<<NNODES / 4, 256, 0, stream>>>(x16, row_ptr, edge_src, deg_inv, agg16);
    k_gemm_mfma<128, true, true><<<NBLK_GEMM, 256, 0, stream>>>(x16, agg16, Wb0, b0, h1);
    // layer 1: h1 -> h2
    k_aggregate16<<<NNODES / 4, 256, 0, stream>>>(h1, row_ptr, edge_src, deg_inv, agg16);
    k_gemm_mfma<128, true, true><<<NBLK_GEMM, 256, 0, stream>>>(h1, agg16, Wb1, b1, h2);
    // layer 2: h2 -> out (fp32)
    k_aggregate16<<<NNODES / 4, 256, 0, stream>>>(h2, row_ptr, edge_src, deg_inv, agg16);
    k_gemm_mfma<64, false, false><<<NBLK_GEMM, 256, 0, stream>>>(h2, agg16, Wb2, b2, out);
}

// Round 4
// 474.955 us; speedup vs baseline: 3.2391x; 1.3068x over previous
//
#include <hip/hip_runtime.h>
#include <hip/hip_fp16.h>

#define NNODES 100000
#define NPAD   100032            // 64*1563, padded so GEMM A-loads need no mask
#define NEDGES 1600000
#define NBLK_GEMM (NPAD / 64)    // 1563

#define BKT   512                // nodes per bucket
#define NBKT  ((NNODES + BKT - 1) / BKT)   // 196
#define CAP   10240              // slab capacity (mean 8192, sigma~90 -> 22 sigma)
#define EPB   8192               // edges per block, pass A
#define NBLK_A ((NEDGES + EPB - 1) / EPB)  // 196

typedef _Float16 half8 __attribute__((ext_vector_type(8)));
typedef _Float16 half4v __attribute__((ext_vector_type(4)));
typedef float floatx4 __attribute__((ext_vector_type(4)));

// ---------------- CSR build: two-level bucket sort ----------------

// pass A: bin edges into per-bucket slabs; packed word = src | (dst&511)<<20
__global__ __launch_bounds__(256) void k_binA(const int* __restrict__ src, const int* __restrict__ dst,
                                              int* __restrict__ gcur, unsigned* __restrict__ pairs) {
    __shared__ int cnt[NBKT];
    __shared__ int cur[NBKT];
    int t = threadIdx.x;
    if (t < NBKT) cnt[t] = 0;
    __syncthreads();
    int e0 = blockIdx.x * EPB;
    for (int i = t; i < EPB; i += 256) {
        int e = e0 + i;
        if (e < NEDGES) atomicAdd(&cnt[dst[e] >> 9], 1);
    }
    __syncthreads();
    if (t < NBKT) {
        int c = cnt[t];
        cur[t] = (c > 0) ? atomicAdd(&gcur[t], c) : 0;   // reserve contiguous chunk in slab
    }
    __syncthreads();
    for (int i = t; i < EPB; i += 256) {
        int e = e0 + i;
        if (e < NEDGES) {
            int d = dst[e];
            int b = d >> 9;
            int pos = atomicAdd(&cur[b], 1);
            pairs[b * CAP + pos] = (unsigned)src[e] | ((unsigned)(d & 511) << 20);
        }
    }
}

// exclusive-scan of 196 bucket totals
__global__ __launch_bounds__(256) void k_bktscan(const int* __restrict__ gcur, int* __restrict__ bkt_base,
                                                 int* __restrict__ row_ptr) {
    __shared__ int lds[256];
    int t = threadIdx.x;
    int v = (t < NBKT) ? gcur[t] : 0;
    lds[t] = v;
    __syncthreads();
#pragma unroll
    for (int off = 1; off < 256; off <<= 1) {
        int u = (t >= off) ? lds[t - off] : 0;
        __syncthreads();
        lds[t] += u;
        __syncthreads();
    }
    if (t < NBKT) bkt_base[t] = lds[t] - v;
    if (t == 0) row_ptr[NNODES] = NEDGES;
}

// pass B: one block per bucket; local 512-node histogram + scan; scatter within
// a 32KB CSR window -> row_ptr, deg_inv, edge_src
__global__ __launch_bounds__(256) void k_binB(const unsigned* __restrict__ pairs, const int* __restrict__ gcnt,
                                              const int* __restrict__ bkt_base,
                                              int* __restrict__ row_ptr, float* __restrict__ deg_inv,
                                              int* __restrict__ edge_src) {
    __shared__ int hist[BKT];
    __shared__ int pref[BKT];
    __shared__ int sc[256];
    int b = blockIdx.x;
    int t = threadIdx.x;
    int n = gcnt[b];
    int base = bkt_base[b];
    const unsigned* pp = pairs + (size_t)b * CAP;
    hist[t] = 0; hist[t + 256] = 0;
    __syncthreads();
    for (int i = t; i < n; i += 256) atomicAdd(&hist[pp[i] >> 20], 1);
    __syncthreads();
    // 512-wide exclusive scan with 256 threads (2 elems/thread)
    int h0 = hist[2 * t], h1 = hist[2 * t + 1];
    sc[t] = h0 + h1;
    __syncthreads();
#pragma unroll
    for (int off = 1; off < 256; off <<= 1) {
        int u = (t >= off) ? sc[t - off] : 0;
        __syncthreads();
        sc[t] += u;
        __syncthreads();
    }
    int ex = sc[t] - (h0 + h1);
    pref[2 * t] = ex;
    pref[2 * t + 1] = ex + h0;
    __syncthreads();
#pragma unroll
    for (int k2 = 0; k2 < 2; ++k2) {
        int j = t + k2 * 256;
        int node = b * BKT + j;
        int dg = hist[j];
        if (node < NNODES) {
            row_ptr[node] = base + pref[j];
            deg_inv[node] = 1.0f / fmaxf((float)dg, 1.0f);
        }
    }
    __syncthreads();
    hist[t] = pref[t]; hist[t + 256] = pref[t + 256];   // hist -> cursor
    __syncthreads();
    for (int i = t; i < n; i += 256) {
        unsigned p = pp[i];
        int pos = atomicAdd(&hist[p >> 20], 1);
        edge_src[base + pos] = (int)(p & 0xFFFFF);
    }
}

// ---------------- fp32 -> fp16 feature conversion ----------------
__global__ __launch_bounds__(256) void k_f2h(const float* __restrict__ x, __half* __restrict__ x16) {
    int i = blockIdx.x * 256 + threadIdx.x;       // one float4 -> 4 halfs
    if (i < NNODES * 32) {
        float4 v = ((const float4*)x)[i];
        __half2* o = (__half2*)(x16 + (size_t)i * 4);
        o[0] = __floats2half2_rn(v.x, v.y);
        o[1] = __floats2half2_rn(v.z, v.w);
    }
}

// ---------------- W pre-shuffle into MFMA B-fragment order ----------------
template <int COLS>
__global__ __launch_bounds__(256) void k_wshuf(const float* __restrict__ Ws, const float* __restrict__ Wn,
                                               __half* __restrict__ Wb) {
    constexpr int NCT = COLS / 16;
    int t = blockIdx.x * 256 + threadIdx.x;
    if (t >= 8 * NCT * 64) return;
    int lane  = t & 63;
    int ctile = (t >> 6) % NCT;
    int kstep = t / (64 * NCT);
    int n  = ctile * 16 + (lane & 15);
    int k0 = kstep * 32 + (lane >> 4) * 8;
    half8 w8;
#pragma unroll
    for (int j = 0; j < 8; ++j) {
        int k = k0 + j;
        float w = (k < 128) ? Ws[k * COLS + n] : Wn[(k - 128) * COLS + n];
        w8[j] = (_Float16)w;
    }
    ((half8*)Wb)[t] = w8;
}

// ---------------- mean-aggregate v2 ----------------
// wave = one node; two 32-lane halves process even/odd edges; lane loads half4
// (8B) so one VMEM instruction gathers TWO neighbor rows; 4-deep unroll = 8 rows
// in flight. Cross-half combine via shfl_xor(32).
__global__ __launch_bounds__(256) void k_aggregate16(const __half* __restrict__ h,
                                                     const int* __restrict__ row_ptr,
                                                     const int* __restrict__ edge_src,
                                                     const float* __restrict__ deg_inv,
                                                     __half* __restrict__ agg) {
    int node = blockIdx.x * 4 + (threadIdx.x >> 6);
    int lane = threadIdx.x & 63;
    int sub = lane >> 5;       // 0: even edges, 1: odd edges
    int l32 = lane & 31;
    int beg = row_ptr[node];
    int end = row_ptr[node + 1];
    const half4v* hb = (const half4v*)h;      // row = 32 half4
    float4 a0 = {0,0,0,0}, a1 = {0,0,0,0}, a2 = {0,0,0,0}, a3 = {0,0,0,0};
    int p = beg + sub;
    for (; p + 6 < end; p += 8) {
        int s0 = edge_src[p], s1 = edge_src[p + 2], s2 = edge_src[p + 4], s3 = edge_src[p + 6];
        half4v v0 = hb[(size_t)s0 * 32 + l32];
        half4v v1 = hb[(size_t)s1 * 32 + l32];
        half4v v2 = hb[(size_t)s2 * 32 + l32];
        half4v v3 = hb[(size_t)s3 * 32 + l32];
        a0.x += (float)v0[0]; a0.y += (float)v0[1]; a0.z += (float)v0[2]; a0.w += (float)v0[3];
        a1.x += (float)v1[0]; a1.y += (float)v1[1]; a1.z += (float)v1[2]; a1.w += (float)v1[3];
        a2.x += (float)v2[0]; a2.y += (float)v2[1]; a2.z += (float)v2[2]; a2.w += (float)v2[3];
        a3.x += (float)v3[0]; a3.y += (float)v3[1]; a3.z += (float)v3[2]; a3.w += (float)v3[3];
    }
    for (; p < end; p += 2) {
        int s = edge_src[p];
        half4v v = hb[(size_t)s * 32 + l32];
        a0.x += (float)v[0]; a0.y += (float)v[1]; a0.z += (float)v[2]; a0.w += (float)v[3];
    }
    float4 s;
    s.x = (a0.x + a1.x) + (a2.x + a3.x);
    s.y = (a0.y + a1.y) + (a2.y + a3.y);
    s.z = (a0.z + a1.z) + (a2.z + a3.z);
    s.w = (a0.w + a1.w) + (a2.w + a3.w);
    // combine even/odd halves
    s.x += __shfl_xor(s.x, 32, 64);
    s.y += __shfl_xor(s.y, 32, 64);
    s.z += __shfl_xor(s.z, 32, 64);
    s.w += __shfl_xor(s.w, 32, 64);
    if (sub == 0) {
        float di = deg_inv[node];
        half4v o;
        o[0] = (_Float16)(s.x * di); o[1] = (_Float16)(s.y * di);
        o[2] = (_Float16)(s.z * di); o[3] = (_Float16)(s.w * di);
        ((half4v*)agg)[(size_t)node * 32 + l32] = o;
    }
}

// ---------------- MFMA dual-GEMM + bias (+relu) ----------------
template <int COLS, bool RELU, bool OUT16>
__global__ __launch_bounds__(256) void k_gemm_mfma(const __half* __restrict__ Ah,
                                                   const __half* __restrict__ Aa,
                                                   const __half* __restrict__ Wb,
                                                   const float* __restrict__ bias,
                                                   void* __restrict__ outv) {
    constexpr int NCT = COLS / 16;
    int lane = threadIdx.x & 63;
    int wave = threadIdx.x >> 6;
    int row0 = blockIdx.x * 64 + wave * 16;
    int m = lane & 15, quad = lane >> 4;
    const half8* Aq_h = (const half8*)(Ah + (size_t)(row0 + m) * 128 + quad * 8);
    const half8* Aq_a = (const half8*)(Aa + (size_t)(row0 + m) * 128 + quad * 8);
    const half8* Bq = (const half8*)Wb;

    floatx4 acc[NCT];
#pragma unroll
    for (int c = 0; c < NCT; ++c) acc[c] = floatx4{0.f, 0.f, 0.f, 0.f};

#pragma unroll
    for (int ks = 0; ks < 8; ++ks) {
        half8 a = (ks < 4) ? Aq_h[ks * 4] : Aq_a[(ks - 4) * 4];
#pragma unroll
        for (int c = 0; c < NCT; ++c) {
            half8 b = Bq[(size_t)(ks * NCT + c) * 64 + lane];
            acc[c] = __builtin_amdgcn_mfma_f32_16x16x32_f16(a, b, acc[c], 0, 0, 0);
        }
    }

#pragma unroll
    for (int c = 0; c < NCT; ++c) {
        int col = c * 16 + m;
        float bv = bias[col];
#pragma unroll
        for (int r = 0; r < 4; ++r) {
            int row = row0 + quad * 4 + r;
            float v = acc[c][r] + bv;
            if (RELU) v = fmaxf(v, 0.f);
            if (row < NNODES) {
                if (OUT16) ((__half*)outv)[(size_t)row * COLS + col] = __float2half(v);
                else       ((float*)outv)[(size_t)row * COLS + col] = v;
            }
        }
    }
}

// ---------------- launch ----------------

extern "C" void kernel_launch(void* const* d_in, const int* in_sizes, int n_in,
                              void* d_out, int out_size, void* d_ws, size_t ws_size,
                              hipStream_t stream) {
    const float* x   = (const float*)d_in[0];
    const int*   src = (const int*)d_in[1];
    const int*   dst = (const int*)d_in[2];
    const float* Ws0 = (const float*)d_in[3];
    const float* Wn0 = (const float*)d_in[4];
    const float* b0  = (const float*)d_in[5];
    const float* Ws1 = (const float*)d_in[6];
    const float* Wn1 = (const float*)d_in[7];
    const float* b1  = (const float*)d_in[8];
    const float* Ws2 = (const float*)d_in[9];
    const float* Wn2 = (const float*)d_in[10];
    const float* b2  = (const float*)d_in[11];
    float* out = (float*)d_out;

    char* ws = (char*)d_ws;
    size_t off = 0;
    auto alloc = [&](size_t bytes) -> void* {
        off = (off + 255) & ~(size_t)255;
        void* p = ws + off;
        off += bytes;
        return p;
    };
    int*      row_ptr  = (int*)alloc((size_t)(NNODES + 1) * 4);
    float*    deg_inv  = (float*)alloc((size_t)NNODES * 4);
    int*      edge_src = (int*)alloc((size_t)NEDGES * 4);
    int*      gcur     = (int*)alloc((size_t)NBKT * 4);
    int*      bkt_base = (int*)alloc((size_t)(NBKT + 1) * 4);
    unsigned* pairs    = (unsigned*)alloc((size_t)NBKT * CAP * 4);
    __half*   x16      = (__half*)alloc((size_t)NPAD * 128 * 2);
    __half*   agg16    = (__half*)alloc((size_t)NPAD * 128 * 2);
    __half*   h1       = (__half*)alloc((size_t)NPAD * 128 * 2);
    __half*   h2       = (__half*)alloc((size_t)NPAD * 128 * 2);
    __half*   Wb0      = (__half*)alloc((size_t)8 * 8 * 64 * 8 * 2);
    __half*   Wb1      = (__half*)alloc((size_t)8 * 8 * 64 * 8 * 2);
    __half*   Wb2      = (__half*)alloc((size_t)8 * 4 * 64 * 8 * 2);
    (void)ws_size; (void)n_in; (void)in_sizes; (void)out_size;

    // CSR build (bucketed)
    hipMemsetAsync(gcur, 0, (size_t)NBKT * 4, stream);
    k_binA<<<NBLK_A, 256, 0, stream>>>(src, dst, gcur, pairs);
    k_bktscan<<<1, 256, 0, stream>>>(gcur, bkt_base, row_ptr);
    k_binB<<<NBKT, 256, 0, stream>>>(pairs, gcur, bkt_base, row_ptr, deg_inv, edge_src);

    // conversions
    k_f2h<<<(NNODES * 32 + 255) / 256, 256, 0, stream>>>(x, x16);
    k_wshuf<128><<<(8 * 8 * 64 + 255) / 256, 256, 0, stream>>>(Ws0, Wn0, Wb0);
    k_wshuf<128><<<(8 * 8 * 64 + 255) / 256, 256, 0, stream>>>(Ws1, Wn1, Wb1);
    k_wshuf<64><<<(8 * 4 * 64 + 255) / 256, 256, 0, stream>>>(Ws2, Wn2, Wb2);

    // layer 0: x16 -> h1
    k_aggregate16<<<NNODES / 4, 256, 0, stream>>>(x16, row_ptr, edge_src, deg_inv, agg16);
    k_gemm_mfma<128, true, true><<<NBLK_GEMM, 256, 0, stream>>>(x16, agg16, Wb0, b0, h1);
    // layer 1: h1 -> h2
    k_aggregate16<<<NNODES / 4, 256, 0, stream>>>(h1, row_ptr, edge_src, deg_inv, agg16);
    k_gemm_mfma<128, true, true><<<NBLK_GEMM, 256, 0, stream>>>(h1, agg16, Wb1, b1, h2);
    // layer 2: h2 -> out (fp32)
    k_aggregate16<<<NNODES / 4, 256, 0, stream>>>(h2, row_ptr, edge_src, deg_inv, agg16);
    k_gemm_mfma<64, false, false><<<NBLK_GEMM, 256, 0, stream>>>(h2, agg16, Wb2, b2, out);
}

// Round 5
// 467.832 us; speedup vs baseline: 3.2884x; 1.0152x over previous
//
#include <hip/hip_runtime.h>
#include <hip/hip_fp16.h>

#define NNODES 100000
#define NPAD   100032            // 64*1563, padded so GEMM A-loads need no mask
#define NEDGES 1600000
#define NBLK_GEMM (NPAD / 64)    // 1563

#define BKT   512                // nodes per bucket
#define NBKT  ((NNODES + BKT - 1) / BKT)   // 196
#define CAP   10240              // slab capacity (mean 8192, 22 sigma slack)
#define EPB   2048               // edges per block, pass A (782 blocks)
#define NBLK_A ((NEDGES + EPB - 1) / EPB)

typedef _Float16 half8 __attribute__((ext_vector_type(8)));
typedef _Float16 half4v __attribute__((ext_vector_type(4)));
typedef float floatx4 __attribute__((ext_vector_type(4)));

// ---------------- CSR build: two-level bucket sort ----------------

// pass A: bin edges into per-bucket slabs; packed word = src | (dst&511)<<20
__global__ __launch_bounds__(256) void k_binA(const int* __restrict__ src, const int* __restrict__ dst,
                                              int* __restrict__ gcur, unsigned* __restrict__ pairs) {
    __shared__ int cnt[NBKT];
    __shared__ int cur[NBKT];
    int t = threadIdx.x;
    if (t < NBKT) cnt[t] = 0;
    __syncthreads();
    int e0 = blockIdx.x * EPB;
    for (int i = t; i < EPB; i += 256) {
        int e = e0 + i;
        if (e < NEDGES) atomicAdd(&cnt[dst[e] >> 9], 1);
    }
    __syncthreads();
    if (t < NBKT) {
        int c = cnt[t];
        cur[t] = (c > 0) ? atomicAdd(&gcur[t], c) : 0;   // reserve contiguous chunk
    }
    __syncthreads();
    for (int i = t; i < EPB; i += 256) {
        int e = e0 + i;
        if (e < NEDGES) {
            int d = dst[e];
            int b = d >> 9;
            int pos = atomicAdd(&cur[b], 1);
            pairs[b * CAP + pos] = (unsigned)src[e] | ((unsigned)(d & 511) << 20);
        }
    }
}

// exclusive-scan of 196 bucket totals
__global__ __launch_bounds__(256) void k_bktscan(const int* __restrict__ gcur, int* __restrict__ bkt_base,
                                                 int* __restrict__ row_ptr) {
    __shared__ int lds[256];
    int t = threadIdx.x;
    int v = (t < NBKT) ? gcur[t] : 0;
    lds[t] = v;
    __syncthreads();
#pragma unroll
    for (int off = 1; off < 256; off <<= 1) {
        int u = (t >= off) ? lds[t - off] : 0;
        __syncthreads();
        lds[t] += u;
        __syncthreads();
    }
    if (t < NBKT) bkt_base[t] = lds[t] - v;
    if (t == 0) row_ptr[NNODES] = NEDGES;
}

// pass B: one block (512 thr) per bucket; 512-node histogram + scan; scatter
// within a 32KB CSR window -> row_ptr, deg_inv, edge_src
__global__ __launch_bounds__(512) void k_binB(const unsigned* __restrict__ pairs, const int* __restrict__ gcnt,
                                              const int* __restrict__ bkt_base,
                                              int* __restrict__ row_ptr, float* __restrict__ deg_inv,
                                              int* __restrict__ edge_src) {
    __shared__ int hist[BKT];
    __shared__ int sc[BKT];
    int b = blockIdx.x;
    int t = threadIdx.x;
    int n = gcnt[b];
    int base = bkt_base[b];
    const unsigned* pp = pairs + (size_t)b * CAP;
    hist[t] = 0;
    __syncthreads();
    for (int i = t; i < n; i += 512) atomicAdd(&hist[pp[i] >> 20], 1);
    __syncthreads();
    int v = hist[t];
    sc[t] = v;
    __syncthreads();
#pragma unroll
    for (int off = 1; off < 512; off <<= 1) {
        int u = (t >= off) ? sc[t - off] : 0;
        __syncthreads();
        sc[t] += u;
        __syncthreads();
    }
    int pref = sc[t] - v;      // exclusive prefix within bucket
    int node = b * BKT + t;
    if (node < NNODES) {
        row_ptr[node] = base + pref;
        deg_inv[node] = 1.0f / fmaxf((float)v, 1.0f);
    }
    __syncthreads();
    hist[t] = pref;            // hist -> cursor
    __syncthreads();
    for (int i = t; i < n; i += 512) {
        unsigned p = pp[i];
        int pos = atomicAdd(&hist[p >> 20], 1);
        edge_src[base + pos] = (int)(p & 0xFFFFF);
    }
}

// ---------------- fp32 -> fp16 feature conversion ----------------
__global__ __launch_bounds__(256) void k_f2h(const float* __restrict__ x, __half* __restrict__ x16) {
    int i = blockIdx.x * 256 + threadIdx.x;
    if (i < NNODES * 32) {
        float4 v = ((const float4*)x)[i];
        __half2* o = (__half2*)(x16 + (size_t)i * 4);
        o[0] = __floats2half2_rn(v.x, v.y);
        o[1] = __floats2half2_rn(v.z, v.w);
    }
}

// ---------------- W pre-shuffle: [Ws|Wn] K=128 -> MFMA B-fragment order ------
// Wb half8 index t = (kstep*NCT + ctile)*64 + lane; element j is
// Wcat[kstep*32 + (lane>>4)*8 + j][ctile*16 + (lane&15)], Wcat = [Ws | Wn].
template <int C>
__global__ __launch_bounds__(256) void k_wshuf2(const float* __restrict__ Ws, const float* __restrict__ Wn,
                                                __half* __restrict__ Wb) {
    constexpr int NCT = 2 * C / 16;
    int t = blockIdx.x * 256 + threadIdx.x;
    if (t >= 4 * NCT * 64) return;
    int lane  = t & 63;
    int ctile = (t >> 6) % NCT;
    int kstep = t / (64 * NCT);
    int n  = ctile * 16 + (lane & 15);
    int k0 = kstep * 32 + (lane >> 4) * 8;
    half8 w8;
#pragma unroll
    for (int j = 0; j < 8; ++j) {
        int k = k0 + j;
        float w = (n < C) ? Ws[k * C + n] : Wn[k * C + (n - C)];
        w8[j] = (_Float16)w;
    }
    ((half8*)Wb)[t] = w8;
}

// ---------------- MFMA GEMM: h -> zs (=h@Ws+b) and zn (=h@Wn) ----------------
// per-wave 16 rows x 2C cols, K=128 in 4 steps. ZS32: zs stored fp32.
template <int C, bool ZS32>
__global__ __launch_bounds__(256) void k_gemm2(const __half* __restrict__ A,
                                               const __half* __restrict__ Wb,
                                               const float* __restrict__ bias,
                                               void* __restrict__ zs,
                                               __half* __restrict__ zn) {
    constexpr int NCT = 2 * C / 16;
    int lane = threadIdx.x & 63;
    int wave = threadIdx.x >> 6;
    int row0 = blockIdx.x * 64 + wave * 16;
    int m = lane & 15, quad = lane >> 4;
    const half8* Aq = (const half8*)(A + (size_t)(row0 + m) * 128 + quad * 8);
    const half8* Bq = (const half8*)Wb;

    floatx4 acc[NCT];
#pragma unroll
    for (int c = 0; c < NCT; ++c) acc[c] = floatx4{0.f, 0.f, 0.f, 0.f};

#pragma unroll
    for (int ks = 0; ks < 4; ++ks) {
        half8 a = Aq[ks * 4];
#pragma unroll
        for (int c = 0; c < NCT; ++c) {
            half8 b = Bq[(size_t)(ks * NCT + c) * 64 + lane];
            acc[c] = __builtin_amdgcn_mfma_f32_16x16x32_f16(a, b, acc[c], 0, 0, 0);
        }
    }

#pragma unroll
    for (int c = 0; c < NCT; ++c) {
        bool is_self = (c < NCT / 2);
        int col = (is_self ? c : c - NCT / 2) * 16 + m;
        float bv = is_self ? bias[col] : 0.f;
#pragma unroll
        for (int r = 0; r < 4; ++r) {
            int row = row0 + quad * 4 + r;
            if (row < NNODES) {
                float v = acc[c][r] + bv;
                if (is_self) {
                    if (ZS32) ((float*)zs)[(size_t)row * C + col] = v;
                    else      ((__half*)zs)[(size_t)row * C + col] = __float2half(v);
                } else {
                    zn[(size_t)row * C + col] = __float2half(v);
                }
            }
        }
    }
}

// ---------------- gather-add: out = [relu](zs + deg_inv * sum zn[src]) -------
// wave = one node; NSUB subgroups of LPR lanes process interleaved edges; each
// lane loads half4 (8B) so one VMEM op gathers NSUB rows; 8 rows in flight.
template <int C, bool RELU, bool ZS32>
__global__ __launch_bounds__(256) void k_aggadd(const __half* __restrict__ zn,
                                                const void* __restrict__ zs,
                                                const int* __restrict__ row_ptr,
                                                const int* __restrict__ edge_src,
                                                const float* __restrict__ deg_inv,
                                                void* __restrict__ outv) {
    constexpr int LPR  = C / 4;     // lanes per row (32 for C=128, 16 for C=64)
    constexpr int NSUB = 64 / LPR;  // 2 or 4
    constexpr int UNR  = 8 / NSUB;  // 4 or 2
    int node = blockIdx.x * 4 + (threadIdx.x >> 6);
    int lane = threadIdx.x & 63;
    int su = lane / LPR;
    int lr = lane % LPR;
    int beg = row_ptr[node];
    int end = row_ptr[node + 1];
    const half4v* zb = (const half4v*)zn;
    float4 a[UNR];
#pragma unroll
    for (int u = 0; u < UNR; ++u) a[u] = float4{0.f, 0.f, 0.f, 0.f};

    int p = beg + su;
    for (; p + NSUB * (UNR - 1) < end; p += NSUB * UNR) {
        half4v v[UNR];
#pragma unroll
        for (int u = 0; u < UNR; ++u) v[u] = zb[(size_t)edge_src[p + u * NSUB] * LPR + lr];
#pragma unroll
        for (int u = 0; u < UNR; ++u) {
            a[u].x = fmaf((float)v[u][0], 1.0f, a[u].x);
            a[u].y = fmaf((float)v[u][1], 1.0f, a[u].y);
            a[u].z = fmaf((float)v[u][2], 1.0f, a[u].z);
            a[u].w = fmaf((float)v[u][3], 1.0f, a[u].w);
        }
    }
    for (; p < end; p += NSUB) {
        half4v v = zb[(size_t)edge_src[p] * LPR + lr];
        a[0].x = fmaf((float)v[0], 1.0f, a[0].x);
        a[0].y = fmaf((float)v[1], 1.0f, a[0].y);
        a[0].z = fmaf((float)v[2], 1.0f, a[0].z);
        a[0].w = fmaf((float)v[3], 1.0f, a[0].w);
    }
    float4 s = a[0];
#pragma unroll
    for (int u = 1; u < UNR; ++u) { s.x += a[u].x; s.y += a[u].y; s.z += a[u].z; s.w += a[u].w; }
#pragma unroll
    for (int off = 32; off >= LPR; off >>= 1) {
        s.x += __shfl_xor(s.x, off, 64);
        s.y += __shfl_xor(s.y, off, 64);
        s.z += __shfl_xor(s.z, off, 64);
        s.w += __shfl_xor(s.w, off, 64);
    }
    if (su == 0) {
        float di = deg_inv[node];
        float4 self;
        if (ZS32) {
            self = ((const float4*)zs)[(size_t)node * LPR + lr];
        } else {
            half4v z = ((const half4v*)zs)[(size_t)node * LPR + lr];
            self = float4{(float)z[0], (float)z[1], (float)z[2], (float)z[3]};
        }
        float o0 = self.x + s.x * di;
        float o1 = self.y + s.y * di;
        float o2 = self.z + s.z * di;
        float o3 = self.w + s.w * di;
        if (RELU) {
            o0 = fmaxf(o0, 0.f); o1 = fmaxf(o1, 0.f);
            o2 = fmaxf(o2, 0.f); o3 = fmaxf(o3, 0.f);
        }
        if (ZS32) {
            ((float4*)outv)[(size_t)node * LPR + lr] = float4{o0, o1, o2, o3};
        } else {
            half4v o;
            o[0] = (_Float16)o0; o[1] = (_Float16)o1;
            o[2] = (_Float16)o2; o[3] = (_Float16)o3;
            ((half4v*)outv)[(size_t)node * LPR + lr] = o;
        }
    }
}

// ---------------- launch ----------------

extern "C" void kernel_launch(void* const* d_in, const int* in_sizes, int n_in,
                              void* d_out, int out_size, void* d_ws, size_t ws_size,
                              hipStream_t stream) {
    const float* x   = (const float*)d_in[0];
    const int*   src = (const int*)d_in[1];
    const int*   dst = (const int*)d_in[2];
    const float* Ws0 = (const float*)d_in[3];
    const float* Wn0 = (const float*)d_in[4];
    const float* b0  = (const float*)d_in[5];
    const float* Ws1 = (const float*)d_in[6];
    const float* Wn1 = (const float*)d_in[7];
    const float* b1  = (const float*)d_in[8];
    const float* Ws2 = (const float*)d_in[9];
    const float* Wn2 = (const float*)d_in[10];
    const float* b2  = (const float*)d_in[11];
    float* out = (float*)d_out;

    char* ws = (char*)d_ws;
    size_t off = 0;
    auto alloc = [&](size_t bytes) -> void* {
        off = (off + 255) & ~(size_t)255;
        void* p = ws + off;
        off += bytes;
        return p;
    };
    int*      row_ptr  = (int*)alloc((size_t)(NNODES + 1) * 4);
    float*    deg_inv  = (float*)alloc((size_t)NNODES * 4);
    int*      edge_src = (int*)alloc((size_t)NEDGES * 4);
    int*      gcur     = (int*)alloc((size_t)NBKT * 4);
    int*      bkt_base = (int*)alloc((size_t)(NBKT + 1) * 4);
    unsigned* pairs    = (unsigned*)alloc((size_t)NBKT * CAP * 4);
    __half*   x16      = (__half*)alloc((size_t)NPAD * 128 * 2);
    __half*   h1       = (__half*)alloc((size_t)NPAD * 128 * 2);
    __half*   h2       = (__half*)alloc((size_t)NPAD * 128 * 2);
    __half*   zs16     = (__half*)alloc((size_t)NNODES * 128 * 2);
    __half*   zn128    = (__half*)alloc((size_t)NNODES * 128 * 2);
    float*    zs32     = (float*)alloc((size_t)NNODES * 64 * 4);
    __half*   zn64     = (__half*)alloc((size_t)NNODES * 64 * 2);
    __half*   Wb0      = (__half*)alloc((size_t)4 * 16 * 64 * 8 * 2);
    __half*   Wb1      = (__half*)alloc((size_t)4 * 16 * 64 * 8 * 2);
    __half*   Wb2      = (__half*)alloc((size_t)4 * 8 * 64 * 8 * 2);
    (void)ws_size; (void)n_in; (void)in_sizes; (void)out_size;

    // CSR build (bucketed)
    hipMemsetAsync(gcur, 0, (size_t)NBKT * 4, stream);
    k_binA<<<NBLK_A, 256, 0, stream>>>(src, dst, gcur, pairs);
    k_bktscan<<<1, 256, 0, stream>>>(gcur, bkt_base, row_ptr);
    k_binB<<<NBKT, 512, 0, stream>>>(pairs, gcur, bkt_base, row_ptr, deg_inv, edge_src);

    // conversions
    k_f2h<<<(NNODES * 32 + 255) / 256, 256, 0, stream>>>(x, x16);
    k_wshuf2<128><<<(4 * 16 * 64 + 255) / 256, 256, 0, stream>>>(Ws0, Wn0, Wb0);
    k_wshuf2<128><<<(4 * 16 * 64 + 255) / 256, 256, 0, stream>>>(Ws1, Wn1, Wb1);
    k_wshuf2<64><<<(4 * 8 * 64 + 255) / 256, 256, 0, stream>>>(Ws2, Wn2, Wb2);

    // layer 0: x16 -> h1
    k_gemm2<128, false><<<NBLK_GEMM, 256, 0, stream>>>(x16, Wb0, b0, zs16, zn128);
    k_aggadd<128, true, false><<<NNODES / 4, 256, 0, stream>>>(zn128, zs16, row_ptr, edge_src, deg_inv, h1);
    // layer 1: h1 -> h2
    k_gemm2<128, false><<<NBLK_GEMM, 256, 0, stream>>>(h1, Wb1, b1, zs16, zn128);
    k_aggadd<128, true, false><<<NNODES / 4, 256, 0, stream>>>(zn128, zs16, row_ptr, edge_src, deg_inv, h2);
    // layer 2: h2 -> out (fp32), gather width 64
    k_gemm2<64, true><<<NBLK_GEMM, 256, 0, stream>>>(h2, Wb2, b2, zs32, zn64);
    k_aggadd<64, false, true><<<NNODES / 4, 256, 0, stream>>>(zn64, zs32, row_ptr, edge_src, deg_inv, out);
}

// Round 7
// 467.197 us; speedup vs baseline: 3.2928x; 1.0014x over previous
//
#include <hip/hip_runtime.h>
#include <hip/hip_fp16.h>

#define NNODES 100000
#define NPAD   100032            // 64*1563, padded so GEMM A-loads need no mask
#define NEDGES 1600000
#define NBLK_GEMM (NPAD / 64)    // 1563

#define BKT   512                // nodes per bucket
#define NBKT  ((NNODES + BKT - 1) / BKT)   // 196
#define CAP   10240              // slab capacity (mean 8192, 22 sigma slack)
#define EPB   2048               // edges per block, pass A (782 blocks)
#define NBLK_A ((NEDGES + EPB - 1) / EPB)

typedef _Float16 half8 __attribute__((ext_vector_type(8)));
typedef float floatx4 __attribute__((ext_vector_type(4)));

// ---------------- CSR build: two-level bucket sort (R4, verbatim) ------------

__global__ __launch_bounds__(256) void k_binA(const int* __restrict__ src, const int* __restrict__ dst,
                                              int* __restrict__ gcur, unsigned* __restrict__ pairs) {
    __shared__ int cnt[NBKT];
    __shared__ int cur[NBKT];
    int t = threadIdx.x;
    if (t < NBKT) cnt[t] = 0;
    __syncthreads();
    int e0 = blockIdx.x * EPB;
    for (int i = t; i < EPB; i += 256) {
        int e = e0 + i;
        if (e < NEDGES) atomicAdd(&cnt[dst[e] >> 9], 1);
    }
    __syncthreads();
    if (t < NBKT) {
        int c = cnt[t];
        cur[t] = (c > 0) ? atomicAdd(&gcur[t], c) : 0;
    }
    __syncthreads();
    for (int i = t; i < EPB; i += 256) {
        int e = e0 + i;
        if (e < NEDGES) {
            int d = dst[e];
            int b = d >> 9;
            int pos = atomicAdd(&cur[b], 1);
            pairs[b * CAP + pos] = (unsigned)src[e] | ((unsigned)(d & 511) << 20);
        }
    }
}

__global__ __launch_bounds__(256) void k_bktscan(const int* __restrict__ gcur, int* __restrict__ bkt_base,
                                                 int* __restrict__ row_ptr) {
    __shared__ int lds[256];
    int t = threadIdx.x;
    int v = (t < NBKT) ? gcur[t] : 0;
    lds[t] = v;
    __syncthreads();
#pragma unroll
    for (int off = 1; off < 256; off <<= 1) {
        int u = (t >= off) ? lds[t - off] : 0;
        __syncthreads();
        lds[t] += u;
        __syncthreads();
    }
    if (t < NBKT) bkt_base[t] = lds[t] - v;
    if (t == 0) row_ptr[NNODES] = NEDGES;
}

__global__ __launch_bounds__(512) void k_binB(const unsigned* __restrict__ pairs, const int* __restrict__ gcnt,
                                              const int* __restrict__ bkt_base,
                                              int* __restrict__ row_ptr, float* __restrict__ deg_inv,
                                              int* __restrict__ edge_src) {
    __shared__ int hist[BKT];
    __shared__ int sc[BKT];
    int b = blockIdx.x;
    int t = threadIdx.x;
    int n = gcnt[b];
    int base = bkt_base[b];
    const unsigned* pp = pairs + (size_t)b * CAP;
    hist[t] = 0;
    __syncthreads();
    for (int i = t; i < n; i += 512) atomicAdd(&hist[pp[i] >> 20], 1);
    __syncthreads();
    int v = hist[t];
    sc[t] = v;
    __syncthreads();
#pragma unroll
    for (int off = 1; off < 512; off <<= 1) {
        int u = (t >= off) ? sc[t - off] : 0;
        __syncthreads();
        sc[t] += u;
        __syncthreads();
    }
    int pref = sc[t] - v;
    int node = b * BKT + t;
    if (node < NNODES) {
        row_ptr[node] = base + pref;
        deg_inv[node] = 1.0f / fmaxf((float)v, 1.0f);
    }
    __syncthreads();
    hist[t] = pref;
    __syncthreads();
    for (int i = t; i < n; i += 512) {
        unsigned p = pp[i];
        int pos = atomicAdd(&hist[p >> 20], 1);
        edge_src[base + pos] = (int)(p & 0xFFFFF);
    }
}

// ---------------- fused prep: f2h + 3x wshuf (R4 math, one launch) -----------
// Wb half8 index t = (kstep*NCT + ctile)*64 + lane; element j is
// Wcat[kstep*32 + (lane>>4)*8 + j][ctile*16 + (lane&15)], Wcat = [Ws | Wn].
template <int C>
__device__ inline void wshuf_one(const float* __restrict__ Ws, const float* __restrict__ Wn,
                                 __half* __restrict__ Wb, int t) {
    constexpr int NCT = 2 * C / 16;
    int lane  = t & 63;
    int ctile = (t >> 6) % NCT;
    int kstep = t / (64 * NCT);
    int n  = ctile * 16 + (lane & 15);
    int k0 = kstep * 32 + (lane >> 4) * 8;
    half8 w8;
#pragma unroll
    for (int j = 0; j < 8; ++j) {
        int k = k0 + j;
        float w = (n < C) ? Ws[k * C + n] : Wn[k * C + (n - C)];
        w8[j] = (_Float16)w;
    }
    ((half8*)Wb)[t] = w8;
}

#define F2H_BLK 12500   // NNODES*128 floats = 3.2M float4 / 256

__global__ __launch_bounds__(256) void k_prep(const float* __restrict__ x, __half* __restrict__ x16,
                                              const float* __restrict__ Ws0, const float* __restrict__ Wn0, __half* __restrict__ Wb0,
                                              const float* __restrict__ Ws1, const float* __restrict__ Wn1, __half* __restrict__ Wb1,
                                              const float* __restrict__ Ws2, const float* __restrict__ Wn2, __half* __restrict__ Wb2) {
    int blk = blockIdx.x;
    if (blk < F2H_BLK) {
        int i = blk * 256 + threadIdx.x;   // one float4 -> 4 halfs
        float4 v = ((const float4*)x)[i];
        __half2* o = (__half2*)(x16 + (size_t)i * 4);
        o[0] = __floats2half2_rn(v.x, v.y);
        o[1] = __floats2half2_rn(v.z, v.w);
    } else if (blk < F2H_BLK + 16) {
        wshuf_one<128>(Ws0, Wn0, Wb0, (blk - F2H_BLK) * 256 + threadIdx.x);
    } else if (blk < F2H_BLK + 32) {
        wshuf_one<128>(Ws1, Wn1, Wb1, (blk - F2H_BLK - 16) * 256 + threadIdx.x);
    } else {
        wshuf_one<64>(Ws2, Wn2, Wb2, (blk - F2H_BLK - 32) * 256 + threadIdx.x);
    }
}

// ---------------- MFMA GEMM (R4, verbatim): zs = h@Ws+b, zn = h@Wn -----------
template <int C, bool ZS32>
__global__ __launch_bounds__(256) void k_gemm2(const __half* __restrict__ A,
                                               const __half* __restrict__ Wb,
                                               const float* __restrict__ bias,
                                               void* __restrict__ zs,
                                               __half* __restrict__ zn) {
    constexpr int NCT = 2 * C / 16;
    int lane = threadIdx.x & 63;
    int wave = threadIdx.x >> 6;
    int row0 = blockIdx.x * 64 + wave * 16;
    int m = lane & 15, quad = lane >> 4;
    const half8* Aq = (const half8*)(A + (size_t)(row0 + m) * 128 + quad * 8);
    const half8* Bq = (const half8*)Wb;

    floatx4 acc[NCT];
#pragma unroll
    for (int c = 0; c < NCT; ++c) acc[c] = floatx4{0.f, 0.f, 0.f, 0.f};

#pragma unroll
    for (int ks = 0; ks < 4; ++ks) {
        half8 a = Aq[ks * 4];
#pragma unroll
        for (int c = 0; c < NCT; ++c) {
            half8 b = Bq[(size_t)(ks * NCT + c) * 64 + lane];
            acc[c] = __builtin_amdgcn_mfma_f32_16x16x32_f16(a, b, acc[c], 0, 0, 0);
        }
    }

#pragma unroll
    for (int c = 0; c < NCT; ++c) {
        bool is_self = (c < NCT / 2);
        int col = (is_self ? c : c - NCT / 2) * 16 + m;
        float bv = is_self ? bias[col] : 0.f;
#pragma unroll
        for (int r = 0; r < 4; ++r) {
            int row = row0 + quad * 4 + r;
            if (row < NNODES) {
                float v = acc[c][r] + bv;
                if (is_self) {
                    if (ZS32) ((float*)zs)[(size_t)row * C + col] = v;
                    else      ((__half*)zs)[(size_t)row * C + col] = __float2half(v);
                } else {
                    zn[(size_t)row * C + col] = __float2half(v);
                }
            }
        }
    }
}

// ---------------- gather-add v3-fp32: out = [relu](zs + deg_inv*sum zn[src]) -
// wave = node; lane loads half8 (16B) so one VMEM gathers NSUB rows; fp32
// accumulate (v_fma_mix), fp32 shuffle reduce. UNR-deep unroll.
template <int C, bool RELU, bool ZS32>
__global__ __launch_bounds__(256) void k_aggadd(const __half* __restrict__ zn,
                                                const void* __restrict__ zs,
                                                const int* __restrict__ row_ptr,
                                                const int* __restrict__ edge_src,
                                                const float* __restrict__ deg_inv,
                                                void* __restrict__ outv) {
    constexpr int LPR  = C / 8;            // half8 chunks per row (16 or 8)
    constexpr int NSUB = 64 / LPR;         // 4 (C=128) or 8 (C=64)
    constexpr int UNR  = (C == 128) ? 4 : 2;  // 16 edges in flight
    int node = blockIdx.x * 4 + (threadIdx.x >> 6);
    int lane = threadIdx.x & 63;
    int su = lane / LPR;
    int lr = lane % LPR;
    int beg = row_ptr[node];
    int end = row_ptr[node + 1];
    const half8* zb = (const half8*)zn;
    float a[UNR][8];
#pragma unroll
    for (int u = 0; u < UNR; ++u)
#pragma unroll
        for (int j = 0; j < 8; ++j) a[u][j] = 0.f;

    int p = beg + su;
    for (; p + NSUB * (UNR - 1) < end; p += NSUB * UNR) {
        half8 v[UNR];
#pragma unroll
        for (int u = 0; u < UNR; ++u) v[u] = zb[(size_t)edge_src[p + u * NSUB] * LPR + lr];
#pragma unroll
        for (int u = 0; u < UNR; ++u)
#pragma unroll
            for (int j = 0; j < 8; ++j) a[u][j] = fmaf((float)v[u][j], 1.0f, a[u][j]);
    }
    for (; p < end; p += NSUB) {
        half8 v = zb[(size_t)edge_src[p] * LPR + lr];
#pragma unroll
        for (int j = 0; j < 8; ++j) a[0][j] = fmaf((float)v[j], 1.0f, a[0][j]);
    }

    float s[8];
#pragma unroll
    for (int j = 0; j < 8; ++j) {
        s[j] = a[0][j];
#pragma unroll
        for (int u = 1; u < UNR; ++u) s[j] += a[u][j];
    }
#pragma unroll
    for (int off = 32; off >= LPR; off >>= 1) {
#pragma unroll
        for (int j = 0; j < 8; ++j) s[j] += __shfl_xor(s[j], off, 64);
    }

    if (su == 0) {
        float di = deg_inv[node];
        float o[8];
        if (ZS32) {
            const float4* zp = (const float4*)zs + (size_t)node * (C / 4) + lr * 2;
            float4 z0 = zp[0], z1 = zp[1];
            o[0] = z0.x + s[0] * di; o[1] = z0.y + s[1] * di;
            o[2] = z0.z + s[2] * di; o[3] = z0.w + s[3] * di;
            o[4] = z1.x + s[4] * di; o[5] = z1.y + s[5] * di;
            o[6] = z1.z + s[6] * di; o[7] = z1.w + s[7] * di;
        } else {
            half8 z = ((const half8*)zs)[(size_t)node * LPR + lr];
#pragma unroll
            for (int j = 0; j < 8; ++j) o[j] = (float)z[j] + s[j] * di;
        }
        if (RELU) {
#pragma unroll
            for (int j = 0; j < 8; ++j) o[j] = fmaxf(o[j], 0.f);
        }
        if (ZS32) {
            float4* op = (float4*)outv + (size_t)node * (C / 4) + lr * 2;
            op[0] = float4{o[0], o[1], o[2], o[3]};
            op[1] = float4{o[4], o[5], o[6], o[7]};
        } else {
            half8 h;
#pragma unroll
            for (int j = 0; j < 8; ++j) h[j] = (_Float16)o[j];
            ((half8*)outv)[(size_t)node * LPR + lr] = h;
        }
    }
}

// ---------------- launch ----------------

extern "C" void kernel_launch(void* const* d_in, const int* in_sizes, int n_in,
                              void* d_out, int out_size, void* d_ws, size_t ws_size,
                              hipStream_t stream) {
    const float* x   = (const float*)d_in[0];
    const int*   src = (const int*)d_in[1];
    const int*   dst = (const int*)d_in[2];
    const float* Ws0 = (const float*)d_in[3];
    const float* Wn0 = (const float*)d_in[4];
    const float* b0  = (const float*)d_in[5];
    const float* Ws1 = (const float*)d_in[6];
    const float* Wn1 = (const float*)d_in[7];
    const float* b1  = (const float*)d_in[8];
    const float* Ws2 = (const float*)d_in[9];
    const float* Wn2 = (const float*)d_in[10];
    const float* b2  = (const float*)d_in[11];
    float* out = (float*)d_out;

    char* ws = (char*)d_ws;
    size_t off = 0;
    auto alloc = [&](size_t bytes) -> void* {
        off = (off + 255) & ~(size_t)255;
        void* p = ws + off;
        off += bytes;
        return p;
    };
    int*      row_ptr  = (int*)alloc((size_t)(NNODES + 1) * 4);
    float*    deg_inv  = (float*)alloc((size_t)NNODES * 4);
    int*      edge_src = (int*)alloc((size_t)NEDGES * 4);
    int*      gcur     = (int*)alloc((size_t)NBKT * 4);
    int*      bkt_base = (int*)alloc((size_t)(NBKT + 1) * 4);
    unsigned* pairs    = (unsigned*)alloc((size_t)NBKT * CAP * 4);
    __half*   x16      = (__half*)alloc((size_t)NPAD * 128 * 2);
    __half*   h1       = (__half*)alloc((size_t)NPAD * 128 * 2);
    __half*   h2       = (__half*)alloc((size_t)NPAD * 128 * 2);
    __half*   zs16     = (__half*)alloc((size_t)NNODES * 128 * 2);
    __half*   zn128    = (__half*)alloc((size_t)NNODES * 128 * 2);
    float*    zs32     = (float*)alloc((size_t)NNODES * 64 * 4);
    __half*   zn64     = (__half*)alloc((size_t)NNODES * 64 * 2);
    __half*   Wb0      = (__half*)alloc((size_t)4 * 16 * 64 * 8 * 2);
    __half*   Wb1      = (__half*)alloc((size_t)4 * 16 * 64 * 8 * 2);
    __half*   Wb2      = (__half*)alloc((size_t)4 * 8 * 64 * 8 * 2);
    (void)ws_size; (void)n_in; (void)in_sizes; (void)out_size;

    // CSR build (bucketed)
    hipMemsetAsync(gcur, 0, (size_t)NBKT * 4, stream);
    k_binA<<<NBLK_A, 256, 0, stream>>>(src, dst, gcur, pairs);
    k_bktscan<<<1, 256, 0, stream>>>(gcur, bkt_base, row_ptr);
    k_binB<<<NBKT, 512, 0, stream>>>(pairs, gcur, bkt_base, row_ptr, deg_inv, edge_src);

    // prep: f2h + 3x wshuf fused
    k_prep<<<F2H_BLK + 40, 256, 0, stream>>>(x, x16, Ws0, Wn0, Wb0, Ws1, Wn1, Wb1, Ws2, Wn2, Wb2);

    // layer 0: x16 -> h1
    k_gemm2<128, false><<<NBLK_GEMM, 256, 0, stream>>>(x16, Wb0, b0, zs16, zn128);
    k_aggadd<128, true, false><<<NNODES / 4, 256, 0, stream>>>(zn128, zs16, row_ptr, edge_src, deg_inv, h1);
    // layer 1: h1 -> h2
    k_gemm2<128, false><<<NBLK_GEMM, 256, 0, stream>>>(h1, Wb1, b1, zs16, zn128);
    k_aggadd<128, true, false><<<NNODES / 4, 256, 0, stream>>>(zn128, zs16, row_ptr, edge_src, deg_inv, h2);
    // layer 2: h2 -> out (fp32), gather width 64
    k_gemm2<64, true><<<NBLK_GEMM, 256, 0, stream>>>(h2, Wb2, b2, zs32, zn64);
    k_aggadd<64, false, true><<<NNODES / 4, 256, 0, stream>>>(zn64, zs32, row_ptr, edge_src, deg_inv, out);
}